// Round 4
// baseline (125.889 us; speedup 1.0000x reference)
//
#include <hip/hip_runtime.h>
#include <math.h>

// CapLayer, fused, fence-free — CALIBRATION ROUND: kernel body byte-identical
// to R3; the (memset, kernel) pair is enqueued TWICE per launch so that
//   dur_R4 = floor + 2*slice,  dur_R3 = floor + slice
// pins down the harness floor vs our slice exactly. Second invocation
// re-zeroes acc/cnt and recomputes the identical output (idempotent).
//
// Math (routing degeneracy, b=0 init): output = broadcast_o(squash(colsum/64)),
//   colsum[b,d] = sum_s sum_i W[s,d,i] * U[b,s,i]
//   U[b,s,i]    = sum_{p<256} x[b, s*8192 + p*32 + i]

__global__ __launch_bounds__(256) void k_caplayer(const float* __restrict__ x,
                                                  const float* __restrict__ W,
                                                  float* __restrict__ out,
                                                  float* __restrict__ acc,
                                                  int* __restrict__ cnt) {
    const int blk = blockIdx.x;          // b*32 + s
    const int b   = blk >> 5;
    const int s   = blk & 31;
    const int t   = threadIdx.x;
    const int wv  = t >> 6;              // wave 0..3
    const int ln  = t & 63;

    // ---- Phase A: reduce 256 rows x 32 cols -> U[32] ----
    const float* xb = x + (size_t)blk * 8192;
    float4 a = make_float4(0.f, 0.f, 0.f, 0.f);
#pragma unroll
    for (int k = 0; k < 8; ++k) {        // float4 idx t+256k: i4 = t&7 const
        const float4 v = *reinterpret_cast<const float4*>(xb + (size_t)(t + 256 * k) * 4);
        a.x += v.x; a.y += v.y; a.z += v.z; a.w += v.w;
    }
#pragma unroll
    for (int off = 8; off <= 32; off <<= 1) {   // lanes sharing t&7 = same i4
        a.x += __shfl_xor(a.x, off, 64);
        a.y += __shfl_xor(a.y, off, 64);
        a.z += __shfl_xor(a.z, off, 64);
        a.w += __shfl_xor(a.w, off, 64);
    }
    __shared__ float4 wsum[4][8];
    if (ln < 8) wsum[wv][ln] = a;
    __syncthreads();
    __shared__ float Uf[32];
    if (t < 8) {
        const float4 r0 = wsum[0][t], r1 = wsum[1][t], r2 = wsum[2][t], r3 = wsum[3][t];
        float4 u;
        u.x = r0.x + r1.x + r2.x + r3.x;
        u.y = r0.y + r1.y + r2.y + r3.y;
        u.z = r0.z + r1.z + r2.z + r3.z;
        u.w = r0.w + r1.w + r2.w + r3.w;
        *reinterpret_cast<float4*>(Uf + 4 * t) = u;
    }
    __syncthreads();

    // ---- Phase B: partial[d] = sum_i W[s,d,i]*U[i]; atomic into acc ----
    const int d = t & 63;
    const int q = t >> 6;                // i-quarter
    const float4* W4 = reinterpret_cast<const float4*>(W) + ((size_t)s * 512 + d * 8 + q * 2);
    const float4* U4 = reinterpret_cast<const float4*>(Uf) + q * 2;
    const float4 w0 = W4[0], w1 = W4[1];
    const float4 u0 = U4[0], u1 = U4[1];
    const float part = w0.x * u0.x + w0.y * u0.y + w0.z * u0.z + w0.w * u0.w
                     + w1.x * u1.x + w1.y * u1.y + w1.z * u1.z + w1.w * u1.w;
    __shared__ float pb[256];
    pb[t] = part;
    __syncthreads();
    if (t < 64) {
        const float tot = pb[t] + pb[t + 64] + pb[t + 128] + pb[t + 192];
        __hip_atomic_fetch_add(&acc[b * 64 + t], tot,
                               __ATOMIC_RELAXED, __HIP_MEMORY_SCOPE_AGENT);
    }

    // ---- Phase C: completion counter (wave-0 program order + vmcnt only) ----
    __shared__ int lastflag;
    if (t == 0) {
        asm volatile("s_waitcnt vmcnt(0)" ::: "memory");  // acc atomics ack'd
        const int old = __hip_atomic_fetch_add(&cnt[b], 1,
                                               __ATOMIC_RELAXED, __HIP_MEMORY_SCOPE_AGENT);
        lastflag = (old == 31);
    }
    __syncthreads();
    if (lastflag) {
        __shared__ float vsh[64];
        if (t < 64) {
            const float sv = __hip_atomic_load(&acc[b * 64 + t],
                                               __ATOMIC_RELAXED,
                                               __HIP_MEMORY_SCOPE_AGENT);
            const float s1 = sv * (1.0f / 64.0f);
            float sq = s1 * s1;
#pragma unroll
            for (int off = 32; off >= 1; off >>= 1) sq += __shfl_xor(sq, off, 64);
            const float coeff = sqrtf(sq) / (1.0f + sq);  // n^2/(1+n^2)/n
            vsh[t] = s1 * coeff;
        }
        __syncthreads();
        float* ob = out + (size_t)b * 4096;
        const float val = vsh[t & 63];
#pragma unroll
        for (int qq = 0; qq < 16; ++qq) ob[t + 256 * qq] = val;
    }
}

extern "C" void kernel_launch(void* const* d_in, const int* in_sizes, int n_in,
                              void* d_out, int out_size, void* d_ws, size_t ws_size,
                              hipStream_t stream) {
    const float* x = (const float*)d_in[0];   // [64, 1024, 16, 16] fp32
    const float* W = (const float*)d_in[1];   // [32, 64, 32] fp32
    float* out = (float*)d_out;               // [64, 64, 64] fp32
    float* acc = (float*)d_ws;                // [64*64] fp32
    int*   cnt = (int*)((char*)d_ws + 64 * 64 * sizeof(float));  // [64]

    const size_t zbytes = 64 * 64 * sizeof(float) + 64 * sizeof(int);

    // Invocation 1
    hipMemsetAsync(d_ws, 0, zbytes, stream);
    k_caplayer<<<2048, 256, 0, stream>>>(x, W, out, acc, cnt);
    // Invocation 2 (identical; recomputes same output from re-zeroed state)
    hipMemsetAsync(d_ws, 0, zbytes, stream);
    k_caplayer<<<2048, 256, 0, stream>>>(x, W, out, acc, cnt);
}

// Round 5
// 101.509 us; speedup vs baseline: 1.2402x; 1.2402x over previous
//
#include <hip/hip_runtime.h>
#include <math.h>

// CapLayer, fused, contention-free. Routing degeneracy (b=0 -> softmax
// uniform -> o-independent v -> b stays o-constant all 3 iters):
//   out[b,o,:] = squash( colsum(pred[b])/64 )  broadcast over o
//   colsum[b,d] = sum_s sum_i W[s,d,i] * U[b,s,i]
//   U[b,s,i]    = sum_{p<256} x[b, s*8192 + p*32 + i]
//
// R5 changes vs R3 (slice was 24.3us vs ~10us streaming bound):
//  1) ILP: 8 explicit float4 temps (R3 had VGPR_Count=20 -> loads were
//     serialized load->wait->add; now all 8 in flight).
//  2) Tail: agent-scope atomic STOREs to per-block slots part[blk][64]
//     (zero contention; R3 had 131K RMW adds, 32-way serialized/address).
//     Final block per b gathers 32x64 floats with agent loads.
//  3) W fragment prefetched into regs BEFORE the streaming loop.
//  4) memset shrinks to 256B (cnt only; part is write-before-read).

__global__ __launch_bounds__(256) void k_caplayer(const float* __restrict__ x,
                                                  const float* __restrict__ W,
                                                  float* __restrict__ out,
                                                  float* __restrict__ part,
                                                  int* __restrict__ cnt) {
    const int blk = blockIdx.x;          // b*32 + s
    const int b   = blk >> 5;
    const int s   = blk & 31;
    const int t   = threadIdx.x;
    const int wv  = t >> 6;              // wave 0..3
    const int ln  = t & 63;
    const int d   = t & 63;
    const int q   = t >> 6;              // i-quarter 0..3

    // ---- W prefetch (L2/L3-warm after first block; in flight during A) ----
    const float4* W4 = reinterpret_cast<const float4*>(W)
                     + ((size_t)s * 512 + (size_t)d * 8 + q * 2);
    const float4 w0 = W4[0];
    const float4 w1 = W4[1];

    // ---- Phase A: reduce 256 rows x 32 cols -> U[32] ----
    const float4* xp = reinterpret_cast<const float4*>(x) + (size_t)blk * 2048 + t;
    const float4 v0 = xp[0],    v1 = xp[256],  v2 = xp[512],  v3 = xp[768];
    const float4 v4 = xp[1024], v5 = xp[1280], v6 = xp[1536], v7 = xp[1792];
    float4 a;
    a.x = ((v0.x + v1.x) + (v2.x + v3.x)) + ((v4.x + v5.x) + (v6.x + v7.x));
    a.y = ((v0.y + v1.y) + (v2.y + v3.y)) + ((v4.y + v5.y) + (v6.y + v7.y));
    a.z = ((v0.z + v1.z) + (v2.z + v3.z)) + ((v4.z + v5.z) + (v6.z + v7.z));
    a.w = ((v0.w + v1.w) + (v2.w + v3.w)) + ((v4.w + v5.w) + (v6.w + v7.w));
#pragma unroll
    for (int off = 8; off <= 32; off <<= 1) {   // lanes sharing t&7 = same i4
        a.x += __shfl_xor(a.x, off, 64);
        a.y += __shfl_xor(a.y, off, 64);
        a.z += __shfl_xor(a.z, off, 64);
        a.w += __shfl_xor(a.w, off, 64);
    }
    __shared__ float4 wsum[4][8];
    if (ln < 8) wsum[wv][ln] = a;
    __syncthreads();
    __shared__ float Uf[32];
    if (t < 8) {
        const float4 r0 = wsum[0][t], r1 = wsum[1][t], r2 = wsum[2][t], r3 = wsum[3][t];
        float4 u;
        u.x = (r0.x + r1.x) + (r2.x + r3.x);
        u.y = (r0.y + r1.y) + (r2.y + r3.y);
        u.z = (r0.z + r1.z) + (r2.z + r3.z);
        u.w = (r0.w + r1.w) + (r2.w + r3.w);
        *reinterpret_cast<float4*>(Uf + 4 * t) = u;
    }
    __syncthreads();

    // ---- Phase B: partial[d] = sum_i W[s,d,i]*U[i]; store to own slot ----
    const float4* U4 = reinterpret_cast<const float4*>(Uf) + q * 2;
    const float4 u0 = U4[0], u1 = U4[1];
    const float prt = w0.x * u0.x + w0.y * u0.y + w0.z * u0.z + w0.w * u0.w
                    + w1.x * u1.x + w1.y * u1.y + w1.z * u1.z + w1.w * u1.w;
    __shared__ float pb[256];
    pb[t] = prt;
    __syncthreads();
    if (t < 64) {
        const float tot = (pb[t] + pb[t + 64]) + (pb[t + 128] + pb[t + 192]);
        __hip_atomic_store(&part[(size_t)blk * 64 + t], tot,
                           __ATOMIC_RELAXED, __HIP_MEMORY_SCOPE_AGENT);
    }

    // ---- Phase C: completion counter (wave-0 order via vmcnt only) ----
    __shared__ int lastflag;
    if (t == 0) {
        asm volatile("s_waitcnt vmcnt(0)" ::: "memory");  // part stores ack'd
        const int old = __hip_atomic_fetch_add(&cnt[b], 1,
                                               __ATOMIC_RELAXED, __HIP_MEMORY_SCOPE_AGENT);
        lastflag = ((old & 31) == 31);
    }
    __syncthreads();
    if (lastflag) {
        __shared__ float vsh[64];
        if (t < 64) {
            float sv = 0.f;
#pragma unroll
            for (int ss = 0; ss < 32; ++ss) {
                sv += __hip_atomic_load(&part[(size_t)((b << 5) + ss) * 64 + t],
                                        __ATOMIC_RELAXED, __HIP_MEMORY_SCOPE_AGENT);
            }
            const float s1 = sv * (1.0f / 64.0f);
            float sq = s1 * s1;
#pragma unroll
            for (int off = 32; off >= 1; off >>= 1) sq += __shfl_xor(sq, off, 64);
            const float coeff = sqrtf(sq) / (1.0f + sq);  // n^2/(1+n^2)/n
            vsh[t] = s1 * coeff;
        }
        __syncthreads();
        // broadcast: out[b, o, d] = vsh[d]; float4 stores
        float4* ob4 = reinterpret_cast<float4*>(out + (size_t)b * 4096);
        const float4 vv = *reinterpret_cast<const float4*>(vsh + ((4 * t) & 63));
#pragma unroll
        for (int qq = 0; qq < 4; ++qq) ob4[t + 256 * qq] = vv;
    }
}

extern "C" void kernel_launch(void* const* d_in, const int* in_sizes, int n_in,
                              void* d_out, int out_size, void* d_ws, size_t ws_size,
                              hipStream_t stream) {
    const float* x = (const float*)d_in[0];   // [64, 1024, 16, 16] fp32
    const float* W = (const float*)d_in[1];   // [32, 64, 32] fp32
    float* out = (float*)d_out;               // [64, 64, 64] fp32
    int*   cnt  = (int*)d_ws;                 // [64] ints, zeroed each launch
    float* part = (float*)((char*)d_ws + 256);// [2048][64] floats, no init needed

    hipMemsetAsync(d_ws, 0, 256, stream);
    k_caplayer<<<2048, 256, 0, stream>>>(x, W, out, part, cnt);
}